// Round 8
// baseline (357.294 us; speedup 1.0000x reference)
//
#include <hip/hip_runtime.h>

#define B_      2
#define NO_     96
#define T_      50
#define SD_     4
#define NE_     (NO_*(NO_-1))   /* 9120 */
#define F_      64
#define NW_     15

typedef __attribute__((ext_vector_type(8))) short  short8;   /* bf16x8 MFMA frag */
typedef __attribute__((ext_vector_type(4))) float  f32x4;
typedef __attribute__((ext_vector_type(4))) unsigned short u16x4;
typedef __attribute__((ext_vector_type(2))) unsigned int   u32x2;
typedef __attribute__((ext_vector_type(4))) unsigned int   u32x4;

/* ---- ws layout: bf16 pool (ushort) at byte 8192, element offsets ---- */
#define E_CONVA 0        /* [4 conv][4 m][10 kk][64][8]      = 81920 */
#define E_FC1A  81920    /* [4 m][16 kk][64][8] k=kt*64+f    = 32768 */
#define E_RBL   114688   /* rb cond frags [32 nt][2 kk][64][8]=32768 */
#define E_CONDP 147456   /* [3 mb][16 nt][2 kk][64][8]       = 49152 */
#define E_FCP   196608   /* [7 g][4 nt][2 kk][64][8]         = 28672 */
#define E_C0A   225280   /* conv0 A frags [4 m][64][8]       = 2048  */
#define N_BF16  227328
#define HBAR_F32 115712          /* float offset: (8192 + 2*N_BF16)/4 */

/* frag-index bases (element offset / 8) */
#define FI_FC1   10240
#define FI_RBL   14336
#define FI_CONDP 18432
#define FI_FCP   24576
#define FI_C0A   28160

#define XSTRIDE  3456            /* 54*64 ushorts per edge buffer */
#define X0OFF    256             /* x0 staging overlaid in hTb rows 4.. (dead before conv1) */

#define MFMA(a, b, c) __builtin_amdgcn_mfma_f32_16x16x32_bf16(a, b, c, 0, 0, 0)

/* fast swish: v * rcp(1+exp(-v)); v_rcp_f32 ~1ulp, fine vs 1.7e-2 threshold */
__device__ __forceinline__ float swish_(float v) {
    return v * __builtin_amdgcn_rcpf(1.f + __expf(-v));
}

__device__ __forceinline__ unsigned short f2bf(float f) {
    unsigned u = __float_as_uint(f);
    u += 0x7FFFu + ((u >> 16) & 1u);
    return (unsigned short)(u >> 16);
}
__device__ __forceinline__ float bf2f(unsigned short u) {
    return __uint_as_float(((unsigned)u) << 16);
}
/* 2×f32 -> packed bf16 pair in one instr (RNE) */
__device__ __forceinline__ unsigned cvtpk(float lo, float hi) {
    unsigned r;
    asm("v_cvt_pk_bf16_f32 %0, %1, %2" : "=v"(r) : "v"(lo), "v"(hi));
    return r;
}

/* ------------------------------------------------------------------ */
__global__ void prep_kernel(const float* __restrict__ cnnbf_w,
                            const float* __restrict__ rb1w, const float* __restrict__ rb2w,
                            const float* __restrict__ fc1w, const float* __restrict__ fc2w,
                            const float* __restrict__ rbl1w, const float* __restrict__ rbl2w,
                            const float* __restrict__ mll1w, const float* __restrict__ mll2w,
                            const float* __restrict__ mlf1w, const float* __restrict__ mlf2w,
                            float* __restrict__ ws) {
    int e = blockIdx.x * blockDim.x + threadIdx.x;
    if (e >= N_BF16) return;
    unsigned short* bfp = (unsigned short*)((char*)ws + 8192);
    float v;
    if (e < E_FC1A) {                               /* conv A frags (k = tap*64+fi) */
        int r = e & 511, fid = e >> 9;
        int lane = r >> 3, j = r & 7;
        int kk = fid % 10, m = (fid / 10) & 3, c = fid / 40;
        int fo = m*16 + (lane & 15);
        int kidx = kk*32 + (lane >> 4)*8 + j;
        int k = kidx >> 6, fi = kidx & 63;
        int i = c >> 1;
        const float* src = (c & 1) ? rb2w : rb1w;
        v = src[((i*64 + fo)*64 + fi)*5 + k];
    } else if (e < E_RBL) {                         /* fc1 A frags, k = kt*64+f */
        int e2 = e - E_FC1A;
        int r = e2 & 511, fid = e2 >> 9;
        int lane = r >> 3, j = r & 7;
        int kk = fid & 15, m = fid >> 4;
        int fo = m*16 + (lane & 15);
        int k = kk*32 + (lane >> 4)*8 + j;
        int krow = (k & 63)*8 + (k >> 6);           /* original index = f*8 + kt */
        v = fc1w[fo*512 + krow];
    } else if (e < E_CONDP) {                       /* rb cond B frags */
        int e3 = e - E_RBL;
        int j = e3 & 7, lane = (e3 >> 3) & 63, fid = e3 >> 9;
        int kk = fid & 1, nt = fid >> 1;            /* nt in [0,32) */
        int rb = nt >> 4, which = (nt >> 3) & 1, ot = nt & 7;
        int o = ot*16 + (lane & 15);
        int k = kk*32 + (lane >> 4)*8 + j;
        const float* src = which ? rbl2w : rbl1w;
        v = src[(rb*128 + o)*64 + k];
    } else if (e < E_FCP) {                         /* mb cond B frags */
        int e4 = e - E_CONDP;
        int r = e4 & 511, fid = e4 >> 9;            /* fid = (mb*16+nt)*2+kk */
        int lane = r >> 3, j = r & 7;
        int kk = fid & 1, nt = (fid >> 1) & 15, mb = fid >> 5;
        int n = nt*16 + (lane & 15);
        int which = n >> 7, o = n & 127;
        int k = kk*32 + (lane >> 4)*8 + j;
        const float* src = which ? mll2w : mll1w;
        v = src[(mb*128 + o)*64 + k];
    } else if (e < E_C0A) {                         /* tail fc B frags */
        int e5 = e - E_FCP;
        int r = e5 & 511, fid = e5 >> 9;            /* fid = (g*4+nt)*2+kk */
        int lane = r >> 3, j = r & 7;
        int kk = fid & 1, nt = (fid >> 1) & 3, g = fid >> 3;
        int o = nt*16 + (lane & 15);
        int k = kk*32 + (lane >> 4)*8 + j;
        if (g == 0) v = fc2w[o*64 + k];
        else {
            int mb = (g - 1) >> 1;
            const float* src = ((g - 1) & 1) ? mlf2w : mlf1w;
            v = src[(mb*64 + o)*64 + k];
        }
    } else {                                        /* conv0 A frags (K=24 pad 32) */
        int e6 = e - E_C0A;
        int j = e6 & 7, lane = (e6 >> 3) & 63, m = e6 >> 9;
        int fo = m*16 + (lane & 15);
        int k = (lane >> 4)*8 + j;
        int tap = k >> 3, fi = k & 7;
        v = (tap < 3) ? cnnbf_w[(fo*8 + fi)*3 + tap] : 0.f;
    }
    bfp[e] = f2bf(v);
}

/* ---------------- conv 64->64 k=5 via MFMA, wave=(mi,ni), 2 edges --
   A-fragments loaded ONCE per wave and reused for both edges.
   ISCONV2: residual accumulate via bf16 LDS RMW (own slot, no conflict). */
template<bool ISCONV2>
__device__ __forceinline__ void convpass2e(const short8* __restrict__ AF, int fb,
        const unsigned short* __restrict__ Bb, unsigned short* __restrict__ Db,
        const float* __restrict__ cb,
        const float* __restrict__ gv0, const float* __restrict__ bv0,
        const float* __restrict__ gv1, const float* __restrict__ bv1,
        const int (&dixs)[2][2], bool skip1,
        int lane, int row0, int g0, int mi, int ni) {
    const int t0a = ni * 32;
    f32x4 acc[2][4];
#pragma unroll
    for (int ed = 0; ed < 2; ++ed)
#pragma unroll
        for (int q = 0; q < 4; ++q) acc[ed][q] = (f32x4){0.f,0.f,0.f,0.f};
#pragma unroll
    for (int kk = 0; kk < 10; ++kk) {
        short8 a0 = AF[fb + ((mi*2 + 0)*10 + kk)*64 + lane];
        short8 a1 = AF[fb + ((mi*2 + 1)*10 + kk)*64 + lane];
        const int c  = ((kk & 1) << 2) + g0;
        const int sa = t0a + row0 + (kk >> 1);
        const int ia = sa*64 + ((c ^ (sa & 7)) << 3);
        int ib;
        if (ni == 0) ib = ia + 1024;
        else { const int sb2 = sa + 2; ib = sb2*64 + ((c ^ (sb2 & 7)) << 3); }
#pragma unroll
        for (int ed = 0; ed < 2; ++ed) {
            const unsigned short* Bs = Bb + ed*XSTRIDE;
            short8 b0 = *(const short8*)&Bs[ia];
            short8 b1 = *(const short8*)&Bs[ib];
            acc[ed][0] = MFMA(a0, b0, acc[ed][0]);
            acc[ed][1] = MFMA(a0, b1, acc[ed][1]);
            acc[ed][2] = MFMA(a1, b0, acc[ed][2]);
            acc[ed][3] = MFMA(a1, b1, acc[ed][3]);
        }
    }
#pragma unroll
    for (int ed = 0; ed < 2; ++ed) {
        const float* gv = ed ? gv1 : gv0;
        const float* bv = ed ? bv1 : bv0;
        unsigned short* Dst = Db + ed*XSTRIDE;
#pragma unroll
        for (int a = 0; a < 2; ++a) {
            const int fo0 = (mi*2 + a)*16 + g0*4;
            const f32x4 cb4 = *(const f32x4*)&cb[fo0];
            const f32x4 g4  = *(const f32x4*)&gv[fo0];
            const f32x4 b4  = *(const f32x4*)&bv[fo0];
            f32x4 gcb;
            gcb[0] = g4[0]*cb4[0] + b4[0]; gcb[1] = g4[1]*cb4[1] + b4[1];
            gcb[2] = g4[2]*cb4[2] + b4[2]; gcb[3] = g4[3]*cb4[3] + b4[3];
#pragma unroll
            for (int n = 0; n < 2; ++n) {
                if (n == 1 && skip1) continue;
                const f32x4 A = acc[ed][a*2 + n];
                float s0 = swish_(g4[0]*A[0] + gcb[0]);
                float s1 = swish_(g4[1]*A[1] + gcb[1]);
                float s2 = swish_(g4[2]*A[2] + gcb[2]);
                float s3 = swish_(g4[3]*A[3] + gcb[3]);
                if (ISCONV2) {                       /* residual RMW, own slot */
                    u16x4 old = *(u16x4*)&Dst[dixs[a][n]];
                    s0 += bf2f(old[0]); s1 += bf2f(old[1]);
                    s2 += bf2f(old[2]); s3 += bf2f(old[3]);
                }
                *(u32x2*)&Dst[dixs[a][n]] = (u32x2){cvtpk(s0, s1), cvtpk(s2, s3)};
            }
        }
    }
}

/* ------------------------------------------------------------------ */
__global__ __launch_bounds__(256, 5) void mega_kernel(
    const float* __restrict__ states, const float* __restrict__ latent,
    const float* __restrict__ cnnbf_b,
    const float* __restrict__ rb_conv1_b, const float* __restrict__ rb_conv2_b,
    const float* __restrict__ rb_lfc1_b, const float* __restrict__ rb_lfc2_b,
    const float* __restrict__ mlp1_fc1_b,
    const int* __restrict__ recv_idx, const int* __restrict__ send_idx,
    const float* __restrict__ ws, float* __restrict__ hbar) {

    const int ge0 = blockIdx.x * 2;                /* two edges per block */
    const int tid  = threadIdx.x;
    const int lane = tid & 63;
    const int wv   = tid >> 6;
    const int row0 = lane & 15, g0 = lane >> 4;
    const int mi = wv & 1, ni = wv >> 1;

    /* LDS = 32000 B -> 5 blocks/CU. x0 staging overlaid inside hTb
       (rows 4..10 per edge slice): dead once conv1 overwrites hTb. */
    __shared__ __align__(16) unsigned short xTb[2*54*64];  /* bf16 trunk, swizzled */
    __shared__ __align__(16) unsigned short hTb[2*54*64];
    __shared__ __align__(16) unsigned short lat_bfb[2*64];
    __shared__ __align__(16) float cond_sb[2*512];

    const unsigned short* bfp = (const unsigned short*)((const char*)ws + 8192);
    const short8* AF = (const short8*)bfp;

    /* per-wave output-tile addresses (invariant across all conv passes) */
    int dixs[2][2];
    const bool skip1 = (ni == 1) && (row0 < 14);
#pragma unroll
    for (int a = 0; a < 2; ++a) {
        const int fo0 = (mi*2 + a)*16 + g0*4;
#pragma unroll
        for (int n = 0; n < 2; ++n) {
            const int t = ((n == 0) ? ni*32 : (ni == 0 ? 16 : 34)) + row0;
            const int rw = t + 2;
            dixs[a][n] = rw*64 + ((((fo0 >> 3) ^ (rw & 7))) << 3) + (fo0 & 7);
        }
    }

    /* ---- stage 0: zero pads, gather both edges ---- */
    for (int z = tid; z < 512; z += 256) {
        const int edz = z >> 8, rr = (z >> 6) & 3, cc = z & 63;
        const int row = (rr < 2) ? rr : 50 + rr;
        xTb[edz*XSTRIDE + row*64 + cc] = 0;
        hTb[edz*XSTRIDE + row*64 + cc] = 0;
    }
    if (tid < 8) {                                   /* x0 pad rows 0,51,52,53 */
        const int edz = tid >> 2, q = tid & 3;
        const int rz = (q == 0) ? 0 : 50 + q;
        short8 zz = {0,0,0,0,0,0,0,0};
        *(short8*)&hTb[edz*XSTRIDE + X0OFF + rz*8] = zz;
    }
    const int b0_ = ge0 / NE_,       e0_ = ge0 % NE_;
    const int b1_ = (ge0+1) / NE_,   e1_ = (ge0+1) % NE_;
    const int rv0 = recv_idx[e0_], sd0 = send_idx[e0_];
    const int rv1 = recv_idx[e1_], sd1 = send_idx[e1_];
    {
        const int ed = tid >> 7, t = tid & 127;      /* one thread per (edge,t) */
        if (t < T_) {
            const int bsel = ed ? b1_ : b0_;
            const int rv = ed ? rv1 : rv0, sd = ed ? sd1 : sd0;
            const f32x4 r4 = *(const f32x4*)&states[((bsel*NO_ + rv)*T_ + t)*SD_];
            const f32x4 s4 = *(const f32x4*)&states[((bsel*NO_ + sd)*T_ + t)*SD_];
            u32x4 q4;
            q4[0] = cvtpk(r4[0], r4[1]); q4[1] = cvtpk(r4[2], r4[3]);
            q4[2] = cvtpk(s4[0], s4[1]); q4[3] = cvtpk(s4[2], s4[3]);
            *(u32x4*)&hTb[ed*XSTRIDE + X0OFF + (t + 1)*8] = q4;
        }
    }
    if (tid < 128) {
        const int edz = tid >> 6, c = tid & 63;
        const int bsel = edz ? b1_ : b0_, esel = edz ? e1_ : e0_;
        lat_bfb[edz*64 + c] = f2bf(latent[(bsel*NE_ + esel)*64 + c]);
    }
    __syncthreads();

    /* ---- stage 1: conv0 via MFMA (A shared) + rb conds (B shared) ---- */
    {
        const int t0a = ni * 32;
        const int sa = t0a + row0 + g0;
        const int sb = (ni == 0) ? (sa + 16) : (sa + 2);
        short8 a0 = AF[FI_C0A + (mi*2 + 0)*64 + lane];
        short8 a1 = AF[FI_C0A + (mi*2 + 1)*64 + lane];
        const f32x4 z4 = {0.f,0.f,0.f,0.f};
#pragma unroll
        for (int ed = 0; ed < 2; ++ed) {
            const unsigned short* xp = hTb + ed*XSTRIDE + X0OFF;
            short8 b0 = *(const short8*)&xp[sa * 8];
            short8 b1 = *(const short8*)&xp[sb * 8];
            f32x4 c00 = MFMA(a0, b0, z4), c01 = MFMA(a0, b1, z4);
            f32x4 c10 = MFMA(a1, b0, z4), c11 = MFMA(a1, b1, z4);
            unsigned short* xw = xTb + ed*XSTRIDE;
#pragma unroll
            for (int a = 0; a < 2; ++a) {
                const int fo0 = (mi*2 + a)*16 + g0*4;
                const f32x4 cb4 = *(const f32x4*)&cnnbf_b[fo0];
#pragma unroll
                for (int n = 0; n < 2; ++n) {
                    if (n == 1 && skip1) continue;
                    const f32x4 A = (a == 0) ? ((n == 0) ? c00 : c01)
                                             : ((n == 0) ? c10 : c11);
                    const float s0 = swish_(A[0] + cb4[0]);
                    const float s1 = swish_(A[1] + cb4[1]);
                    const float s2 = swish_(A[2] + cb4[2]);
                    const float s3 = swish_(A[3] + cb4[3]);
                    *(u32x2*)&xw[dixs[a][n]] = (u32x2){cvtpk(s0, s1), cvtpk(s2, s3)};
                }
            }
        }
        /* rb conds: wave = (rb, which); weight B-frags shared across edges */
        short8 la0_0 = *(const short8*)&lat_bfb[g0 * 8];
        short8 la1_0 = *(const short8*)&lat_bfb[32 + g0 * 8];
        short8 la0_1 = *(const short8*)&lat_bfb[64 + g0 * 8];
        short8 la1_1 = *(const short8*)&lat_bfb[96 + g0 * 8];
        const int rbq = wv >> 1, whq = wv & 1;
        const float* cbias = (whq ? rb_lfc2_b : rb_lfc1_b) + rbq*128;
#pragma unroll
        for (int q8 = 0; q8 < 8; ++q8) {
            short8 w0 = AF[FI_RBL + ((wv*8 + q8)*2 + 0)*64 + lane];
            short8 w1 = AF[FI_RBL + ((wv*8 + q8)*2 + 1)*64 + lane];
            f32x4 d0 = MFMA(la1_0, w1, MFMA(la0_0, w0, z4));
            f32x4 d1 = MFMA(la1_1, w1, MFMA(la0_1, w0, z4));
            if (g0 == 0) {
                const int o = q8*16 + row0;
                cond_sb[rbq*256 + whq*128 + o]       = d0[0] + cbias[o];
                cond_sb[512 + rbq*256 + whq*128 + o] = d1[0] + cbias[o];
            }
        }
    }
    __syncthreads();

    /* ---- stage 2: residual blocks (2 edges interleaved) ---- */
#pragma unroll 1
    for (int rb = 0; rb < 2; ++rb) {
        const float* c0 = cond_sb + rb*256;
        const float* c1 = cond_sb + 512 + rb*256;
        convpass2e<false>(AF, (rb*2 + 0)*2560, xTb, hTb, rb_conv1_b + rb*64,
                          c0, c0 + 64, c1, c1 + 64, dixs, skip1,
                          lane, row0, g0, mi, ni);
        __syncthreads();
        convpass2e<true>(AF, (rb*2 + 1)*2560, hTb, xTb, rb_conv2_b + rb*64,
                         c0 + 128, c0 + 192, c1 + 128, c1 + 192, dixs, skip1,
                         lane, row0, g0, mi, ni);
        __syncthreads();
    }

    /* ---- stage 3: windowed MLP fc1 (A shared) + folded mean ---- */
    {
        const int h = g0, nw = row0;
        f32x4 acc3[2];
        acc3[0] = (f32x4){0.f,0.f,0.f,0.f}; acc3[1] = acc3[0];
        const int nwe = (nw < 15) ? nw : 14;
        const int nwrow = 3*nwe + 2;
#pragma unroll
        for (int kk = 0; kk < 16; ++kk) {
            short8 a = AF[FI_FC1 + (wv*16 + kk)*64 + lane];
            const int row = nwrow + (kk >> 1);
            const int g   = ((kk & 1) << 2) + h;
            const int off = row*64 + ((g ^ (row & 7)) << 3);
#pragma unroll
            for (int ed = 0; ed < 2; ++ed) {
                short8 bfr = *(const short8*)&xTb[ed*XSTRIDE + off];
                acc3[ed] = MFMA(a, bfr, acc3[ed]);
            }
        }
        const f32x4 fb = *(const f32x4*)&mlp1_fc1_b[wv*16 + h*4];
#pragma unroll
        for (int ed = 0; ed < 2; ++ed) {
            float red[4];
#pragma unroll
            for (int r = 0; r < 4; ++r) {
                float v = (nw < 15) ? swish_(acc3[ed][r] + fb[r]) : 0.f;
                v += __shfl_xor(v, 1); v += __shfl_xor(v, 2);
                v += __shfl_xor(v, 4); v += __shfl_xor(v, 8);
                red[r] = v * (1.f / 15.f);
            }
            if (nw == 0) {
                f32x4 o4; o4[0] = red[0]; o4[1] = red[1]; o4[2] = red[2]; o4[3] = red[3];
                *(f32x4*)&hbar[(ge0 + ed)*64 + wv*16 + h*4] = o4;
            }
        }
    }
}

/* ---------------- tail: fc2 + 3 cond-MLP blocks + head, 64 edges/block ---- */
__global__ __launch_bounds__(256) void tail_kernel(
    const float* __restrict__ latent,
    const float* __restrict__ fc2b_g,
    const float* __restrict__ mlf1b, const float* __restrict__ mlf2b,
    const float* __restrict__ mll1b, const float* __restrict__ mll2b,
    const float* __restrict__ em_w, const float* __restrict__ em_b,
    const float* __restrict__ ws, const float* __restrict__ hbar,
    float* __restrict__ out) {

    const int m0 = blockIdx.x * 64;
    const int tid = threadIdx.x, lane = tid & 63, wv = tid >> 6;
    const int row15 = lane & 15, hgp = lane >> 4;
    const int o_l = wv*16 + row15;                 /* this lane's output col */

    __shared__ __align__(16) unsigned short Hb[2][64*64];  /* bf16, swizzled */
    __shared__ float V[64][68];                            /* fp32 running vec */
    __shared__ float em_s[64];

    const unsigned short* bfp = (const unsigned short*)((const char*)ws + 8192);
    const short8* AFp = (const short8*)bfp;

    if (tid < 64) em_s[tid] = em_w[tid];

    /* load hbar -> Hb[0] */
    {
        const int e = tid >> 2, q = tid & 3;
        const f32x4* src = (const f32x4*)&hbar[(m0 + e)*64 + q*16];
#pragma unroll
        for (int v4 = 0; v4 < 4; ++v4) {
            f32x4 x = src[v4];
            const int o0 = q*16 + v4*4;
            const int slot = o0 >> 3, half = (o0 >> 2) & 1;
            u16x4 p; p[0]=f2bf(x[0]); p[1]=f2bf(x[1]); p[2]=f2bf(x[2]); p[3]=f2bf(x[3]);
            *(u16x4*)&Hb[0][e*64 + ((slot ^ (e & 7)) << 3) + half*4] = p;
        }
    }
    __syncthreads();

    /* latent A-frags, cached */
    short8 lf[4][2];
#pragma unroll
    for (int m = 0; m < 4; ++m)
#pragma unroll
        for (int kk = 0; kk < 2; ++kk) {
            const float* lp = &latent[(m0 + m*16 + row15)*64 + kk*32 + hgp*8];
            f32x4 a = *(const f32x4*)lp, c = *(const f32x4*)(lp + 4);
            short8 f;
            f[0]=f2bf(a[0]); f[1]=f2bf(a[1]); f[2]=f2bf(a[2]); f[3]=f2bf(a[3]);
            f[4]=f2bf(c[0]); f[5]=f2bf(c[1]); f[6]=f2bf(c[2]); f[7]=f2bf(c[3]);
            lf[m][kk] = f;
        }

#define RD_A(buf, m, kk) \
    (*(const short8*)&Hb[buf][(m*16 + row15)*64 + ((((kk)*4 + hgp) ^ ((m*16 + row15) & 7)) << 3)])
#define RD_FCP(g, kk)  AFp[FI_FCP + (((g)*4 + wv)*2 + (kk))*64 + lane]
#define RD_CND(mb, nt, kk) AFp[FI_CONDP + (((mb)*16 + (nt))*2 + (kk))*64 + lane]

    /* GEMM0: stage3 fc2 */
    f32x4 D[4];
#pragma unroll
    for (int m = 0; m < 4; ++m) D[m] = (f32x4){0.f,0.f,0.f,0.f};
#pragma unroll
    for (int kk = 0; kk < 2; ++kk) {
        short8 bfr = RD_FCP(0, kk);
#pragma unroll
        for (int m = 0; m < 4; ++m) D[m] = MFMA(RD_A(0, m, kk), bfr, D[m]);
    }
    {
        const float bias = fc2b_g[o_l];
#pragma unroll
        for (int m = 0; m < 4; ++m)
#pragma unroll
            for (int r = 0; r < 4; ++r) {
                const int ee = m*16 + hgp*4 + r;
                const float v = D[m][r] + bias;
                V[ee][o_l] = v;
                Hb[1][ee*64 + ((((o_l >> 3) ^ (ee & 7))) << 3) + (o_l & 7)] = f2bf(v);
            }
    }
    __syncthreads();

    /* 3 cond-MLP blocks */
#pragma unroll 1
    for (int mb = 0; mb < 3; ++mb) {
        f32x4 G1[4], B1[4];
#pragma unroll
        for (int m = 0; m < 4; ++m) { G1[m] = (f32x4){0.f,0.f,0.f,0.f}; B1[m] = G1[m]; }
#pragma unroll
        for (int kk = 0; kk < 2; ++kk) {
            short8 bg = RD_CND(mb, wv,     kk);
            short8 bb = RD_CND(mb, wv + 4, kk);
#pragma unroll
            for (int m = 0; m < 4; ++m) {
                G1[m] = MFMA(lf[m][kk], bg, G1[m]);
                B1[m] = MFMA(lf[m][kk], bb, B1[m]);
            }
        }
        f32x4 D1[4];
#pragma unroll
        for (int m = 0; m < 4; ++m) D1[m] = (f32x4){0.f,0.f,0.f,0.f};
#pragma unroll
        for (int kk = 0; kk < 2; ++kk) {
            short8 bfr = RD_FCP(1 + mb*2, kk);
#pragma unroll
            for (int m = 0; m < 4; ++m) D1[m] = MFMA(RD_A(1, m, kk), bfr, D1[m]);
        }
        {
            const float bfc  = mlf1b[mb*64 + o_l];
            const float bg1  = mll1b[mb*128 + o_l];
            const float bb1  = mll1b[mb*128 + 64 + o_l];
#pragma unroll
            for (int m = 0; m < 4; ++m)
#pragma unroll
                for (int r = 0; r < 4; ++r) {
                    const int ee = m*16 + hgp*4 + r;
                    const float h1 = swish_((G1[m][r] + bg1) * (D1[m][r] + bfc)
                                            + (B1[m][r] + bb1));
                    Hb[0][ee*64 + ((((o_l >> 3) ^ (ee & 7))) << 3) + (o_l & 7)] = f2bf(h1);
                }
        }
        __syncthreads();

        f32x4 G2[4], B2[4];
#pragma unroll
        for (int m = 0; m < 4; ++m) { G2[m] = (f32x4){0.f,0.f,0.f,0.f}; B2[m] = G2[m]; }
#pragma unroll
        for (int kk = 0; kk < 2; ++kk) {
            short8 bg = RD_CND(mb, wv + 8,  kk);
            short8 bb = RD_CND(mb, wv + 12, kk);
#pragma unroll
            for (int m = 0; m < 4; ++m) {
                G2[m] = MFMA(lf[m][kk], bg, G2[m]);
                B2[m] = MFMA(lf[m][kk], bb, B2[m]);
            }
        }
        f32x4 D2[4];
#pragma unroll
        for (int m = 0; m < 4; ++m) D2[m] = (f32x4){0.f,0.f,0.f,0.f};
#pragma unroll
        for (int kk = 0; kk < 2; ++kk) {
            short8 bfr = RD_FCP(2 + mb*2, kk);
#pragma unroll
            for (int m = 0; m < 4; ++m) D2[m] = MFMA(RD_A(0, m, kk), bfr, D2[m]);
        }
        {
            const float bfc  = mlf2b[mb*64 + o_l];
            const float bg2  = mll2b[mb*128 + o_l];
            const float bb2  = mll2b[mb*128 + 64 + o_l];
#pragma unroll
            for (int m = 0; m < 4; ++m)
#pragma unroll
                for (int r = 0; r < 4; ++r) {
                    const int ee = m*16 + hgp*4 + r;
                    const float add = swish_((G2[m][r] + bg2) * (D2[m][r] + bfc)
                                             + (B2[m][r] + bb2));
                    const float vn = V[ee][o_l] + add;
                    V[ee][o_l] = vn;
                    Hb[1][ee*64 + ((((o_l >> 3) ^ (ee & 7))) << 3) + (o_l & 7)] = f2bf(vn);
                }
        }
        __syncthreads();
    }

    /* head */
    if (tid < 64) {
        const int ee = tid;
        float acc = em_b[0];
#pragma unroll 16
        for (int j = 0; j < 64; ++j) {
            const int o = (j + ee) & 63;
            acc += V[ee][o] * em_s[o];
        }
        out[m0 + ee] = acc;
    }
}

extern "C" void kernel_launch(void* const* d_in, const int* in_sizes, int n_in,
                              void* d_out, int out_size, void* d_ws, size_t ws_size,
                              hipStream_t stream) {
    const float* states   = (const float*)d_in[0];
    const float* latent   = (const float*)d_in[1];
    const float* cnnbf_w  = (const float*)d_in[2];
    const float* cnnbf_b  = (const float*)d_in[3];
    const float* rb1w     = (const float*)d_in[4];
    const float* rb1b     = (const float*)d_in[5];
    const float* rb2w     = (const float*)d_in[6];
    const float* rb2b     = (const float*)d_in[7];
    const float* rbl1w    = (const float*)d_in[8];
    const float* rbl1b    = (const float*)d_in[9];
    const float* rbl2w    = (const float*)d_in[10];
    const float* rbl2b    = (const float*)d_in[11];
    const float* fc1w     = (const float*)d_in[12];
    const float* fc1b     = (const float*)d_in[13];
    const float* fc2w     = (const float*)d_in[14];
    const float* fc2b     = (const float*)d_in[15];
    const float* mlf1w    = (const float*)d_in[16];
    const float* mlf1b    = (const float*)d_in[17];
    const float* mlf2w    = (const float*)d_in[18];
    const float* mlf2b    = (const float*)d_in[19];
    const float* mll1w    = (const float*)d_in[20];
    const float* mll1b    = (const float*)d_in[21];
    const float* mll2w    = (const float*)d_in[22];
    const float* mll2b    = (const float*)d_in[23];
    const float* em_w     = (const float*)d_in[24];
    const float* em_b     = (const float*)d_in[25];
    const int*   recv_idx = (const int*)d_in[26];
    const int*   send_idx = (const int*)d_in[27];
    float* ws  = (float*)d_ws;
    float* out = (float*)d_out;
    float* hbar = ws + HBAR_F32;

    prep_kernel<<<(N_BF16 + 255) / 256, 256, 0, stream>>>(
        cnnbf_w, rb1w, rb2w, fc1w, fc2w, rbl1w, rbl2w, mll1w, mll2w, mlf1w, mlf2w, ws);

    mega_kernel<<<B_ * NE_ / 2, 256, 0, stream>>>(
        states, latent, cnnbf_b, rb1b, rb2b, rbl1b, rbl2b, fc1b,
        recv_idx, send_idx, ws, hbar);

    tail_kernel<<<(B_ * NE_) / 64, 256, 0, stream>>>(
        latent, fc2b, mlf1b, mlf2b, mll1b, mll2b, em_w, em_b, ws, hbar, out);
}

// Round 10
// 294.627 us; speedup vs baseline: 1.2127x; 1.2127x over previous
//
#include <hip/hip_runtime.h>

#define B_      2
#define NO_     96
#define T_      50
#define SD_     4
#define NE_     (NO_*(NO_-1))   /* 9120 */
#define F_      64
#define NW_     15

typedef __attribute__((ext_vector_type(8))) short  short8;   /* bf16x8 MFMA frag */
typedef __attribute__((ext_vector_type(4))) float  f32x4;
typedef __attribute__((ext_vector_type(4))) unsigned short u16x4;
typedef __attribute__((ext_vector_type(2))) unsigned int   u32x2;
typedef __attribute__((ext_vector_type(4))) unsigned int   u32x4;

/* ---- ws layout: bf16 pool (ushort) at byte 8192, element offsets ---- */
#define E_CONVA 0        /* [4 conv][4 m][10 kk][64][8]      = 81920 */
#define E_FC1A  81920    /* [4 m][16 kk][64][8] k=kt*64+f    = 32768 */
#define E_RBL   114688   /* rb cond frags [32 nt][2 kk][64][8]=32768 */
#define E_CONDP 147456   /* [3 mb][16 nt][2 kk][64][8]       = 49152 */
#define E_FCP   196608   /* [7 g][4 nt][2 kk][64][8]         = 28672 */
#define E_C0A   225280   /* conv0 A frags [4 m][64][8]       = 2048  */
#define N_BF16  227328
#define HBAR_F32 115712          /* float offset: (8192 + 2*N_BF16)/4 */

/* frag-index bases (element offset / 8) */
#define FI_FC1   10240
#define FI_RBL   14336
#define FI_CONDP 18432
#define FI_FCP   24576
#define FI_C0A   28160

#define XSTRIDE  3456            /* 54*64 ushorts per edge buffer */
#define X0OFF    256             /* x0 staging overlaid in hTb rows 4.. (dead before conv1) */

#define MFMA(a, b, c) __builtin_amdgcn_mfma_f32_16x16x32_bf16(a, b, c, 0, 0, 0)

/* fast swish: v * rcp(1+exp(-v)); v_rcp_f32 ~1ulp, fine vs 1.7e-2 threshold */
__device__ __forceinline__ float swish_(float v) {
    return v * __builtin_amdgcn_rcpf(1.f + __expf(-v));
}

__device__ __forceinline__ unsigned short f2bf(float f) {
    unsigned u = __float_as_uint(f);
    u += 0x7FFFu + ((u >> 16) & 1u);
    return (unsigned short)(u >> 16);
}
__device__ __forceinline__ float bf2f(unsigned short u) {
    return __uint_as_float(((unsigned)u) << 16);
}
/* 2×f32 -> packed bf16 pair in one instr (RNE) — proven in rounds 6-8 */
__device__ __forceinline__ unsigned cvtpk(float lo, float hi) {
    unsigned r;
    asm("v_cvt_pk_bf16_f32 %0, %1, %2" : "=v"(r) : "v"(lo), "v"(hi));
    return r;
}

/* ------------------------------------------------------------------ */
__global__ void prep_kernel(const float* __restrict__ cnnbf_w,
                            const float* __restrict__ rb1w, const float* __restrict__ rb2w,
                            const float* __restrict__ fc1w, const float* __restrict__ fc2w,
                            const float* __restrict__ rbl1w, const float* __restrict__ rbl2w,
                            const float* __restrict__ mll1w, const float* __restrict__ mll2w,
                            const float* __restrict__ mlf1w, const float* __restrict__ mlf2w,
                            float* __restrict__ ws) {
    int e = blockIdx.x * blockDim.x + threadIdx.x;
    if (e >= N_BF16) return;
    unsigned short* bfp = (unsigned short*)((char*)ws + 8192);
    float v;
    if (e < E_FC1A) {                               /* conv A frags (k = tap*64+fi) */
        int r = e & 511, fid = e >> 9;
        int lane = r >> 3, j = r & 7;
        int kk = fid % 10, m = (fid / 10) & 3, c = fid / 40;
        int fo = m*16 + (lane & 15);
        int kidx = kk*32 + (lane >> 4)*8 + j;
        int k = kidx >> 6, fi = kidx & 63;
        int i = c >> 1;
        const float* src = (c & 1) ? rb2w : rb1w;
        v = src[((i*64 + fo)*64 + fi)*5 + k];
    } else if (e < E_RBL) {                         /* fc1 A frags, k = kt*64+f */
        int e2 = e - E_FC1A;
        int r = e2 & 511, fid = e2 >> 9;
        int lane = r >> 3, j = r & 7;
        int kk = fid & 15, m = fid >> 4;
        int fo = m*16 + (lane & 15);
        int k = kk*32 + (lane >> 4)*8 + j;
        int krow = (k & 63)*8 + (k >> 6);           /* original index = f*8 + kt */
        v = fc1w[fo*512 + krow];
    } else if (e < E_CONDP) {                       /* rb cond B frags */
        int e3 = e - E_RBL;
        int j = e3 & 7, lane = (e3 >> 3) & 63, fid = e3 >> 9;
        int kk = fid & 1, nt = fid >> 1;            /* nt in [0,32) */
        int rb = nt >> 4, which = (nt >> 3) & 1, ot = nt & 7;
        int o = ot*16 + (lane & 15);
        int k = kk*32 + (lane >> 4)*8 + j;
        const float* src = which ? rbl2w : rbl1w;
        v = src[(rb*128 + o)*64 + k];
    } else if (e < E_FCP) {                         /* mb cond B frags */
        int e4 = e - E_CONDP;
        int r = e4 & 511, fid = e4 >> 9;            /* fid = (mb*16+nt)*2+kk */
        int lane = r >> 3, j = r & 7;
        int kk = fid & 1, nt = (fid >> 1) & 15, mb = fid >> 5;
        int n = nt*16 + (lane & 15);
        int which = n >> 7, o = n & 127;
        int k = kk*32 + (lane >> 4)*8 + j;
        const float* src = which ? mll2w : mll1w;
        v = src[(mb*128 + o)*64 + k];
    } else if (e < E_C0A) {                         /* tail fc B frags */
        int e5 = e - E_FCP;
        int r = e5 & 511, fid = e5 >> 9;            /* fid = (g*4+nt)*2+kk */
        int lane = r >> 3, j = r & 7;
        int kk = fid & 1, nt = (fid >> 1) & 3, g = fid >> 3;
        int o = nt*16 + (lane & 15);
        int k = kk*32 + (lane >> 4)*8 + j;
        if (g == 0) v = fc2w[o*64 + k];
        else {
            int mb = (g - 1) >> 1;
            const float* src = ((g - 1) & 1) ? mlf2w : mlf1w;
            v = src[(mb*64 + o)*64 + k];
        }
    } else {                                        /* conv0 A frags (K=24 pad 32) */
        int e6 = e - E_C0A;
        int j = e6 & 7, lane = (e6 >> 3) & 63, m = e6 >> 9;
        int fo = m*16 + (lane & 15);
        int k = (lane >> 4)*8 + j;
        int tap = k >> 3, fi = k & 7;
        v = (tap < 3) ? cnnbf_w[(fo*8 + fi)*3 + tap] : 0.f;
    }
    bfp[e] = f2bf(v);
}

/* ---------------- conv 64->64 k=5 via MFMA, wave=(mi,ni), 2 edges --
   A-fragments loaded ONCE per wave and reused for both edges.
   ISCONV2: residual accumulate via bf16 LDS RMW (own slot, no conflict). */
template<bool ISCONV2>
__device__ __forceinline__ void convpass2e(const short8* __restrict__ AF, int fb,
        const unsigned short* __restrict__ Bb, unsigned short* __restrict__ Db,
        const float* __restrict__ cb,
        const float* __restrict__ gv0, const float* __restrict__ bv0,
        const float* __restrict__ gv1, const float* __restrict__ bv1,
        const int (&dixs)[2][2], bool skip1,
        int lane, int row0, int g0, int mi, int ni) {
    const int t0a = ni * 32;
    f32x4 acc[2][4];
#pragma unroll
    for (int ed = 0; ed < 2; ++ed)
#pragma unroll
        for (int q = 0; q < 4; ++q) acc[ed][q] = (f32x4){0.f,0.f,0.f,0.f};
#pragma unroll
    for (int kk = 0; kk < 10; ++kk) {
        short8 a0 = AF[fb + ((mi*2 + 0)*10 + kk)*64 + lane];
        short8 a1 = AF[fb + ((mi*2 + 1)*10 + kk)*64 + lane];
        const int c  = ((kk & 1) << 2) + g0;
        const int sa = t0a + row0 + (kk >> 1);
        const int ia = sa*64 + ((c ^ (sa & 7)) << 3);
        int ib;
        if (ni == 0) ib = ia + 1024;
        else { const int sb2 = sa + 2; ib = sb2*64 + ((c ^ (sb2 & 7)) << 3); }
#pragma unroll
        for (int ed = 0; ed < 2; ++ed) {
            const unsigned short* Bs = Bb + ed*XSTRIDE;
            short8 b0 = *(const short8*)&Bs[ia];
            short8 b1 = *(const short8*)&Bs[ib];
            acc[ed][0] = MFMA(a0, b0, acc[ed][0]);
            acc[ed][1] = MFMA(a0, b1, acc[ed][1]);
            acc[ed][2] = MFMA(a1, b0, acc[ed][2]);
            acc[ed][3] = MFMA(a1, b1, acc[ed][3]);
        }
    }
#pragma unroll
    for (int ed = 0; ed < 2; ++ed) {
        const float* gv = ed ? gv1 : gv0;
        const float* bv = ed ? bv1 : bv0;
        unsigned short* Dst = Db + ed*XSTRIDE;
#pragma unroll
        for (int a = 0; a < 2; ++a) {
            const int fo0 = (mi*2 + a)*16 + g0*4;
            const f32x4 cb4 = *(const f32x4*)&cb[fo0];
            const f32x4 g4  = *(const f32x4*)&gv[fo0];
            const f32x4 b4  = *(const f32x4*)&bv[fo0];
            f32x4 gcb;
            gcb[0] = g4[0]*cb4[0] + b4[0]; gcb[1] = g4[1]*cb4[1] + b4[1];
            gcb[2] = g4[2]*cb4[2] + b4[2]; gcb[3] = g4[3]*cb4[3] + b4[3];
#pragma unroll
            for (int n = 0; n < 2; ++n) {
                if (n == 1 && skip1) continue;
                const f32x4 A = acc[ed][a*2 + n];
                float s0 = swish_(g4[0]*A[0] + gcb[0]);
                float s1 = swish_(g4[1]*A[1] + gcb[1]);
                float s2 = swish_(g4[2]*A[2] + gcb[2]);
                float s3 = swish_(g4[3]*A[3] + gcb[3]);
                if (ISCONV2) {                       /* residual RMW, own slot */
                    u16x4 old = *(u16x4*)&Dst[dixs[a][n]];
                    s0 += bf2f(old[0]); s1 += bf2f(old[1]);
                    s2 += bf2f(old[2]); s3 += bf2f(old[3]);
                }
                *(u32x2*)&Dst[dixs[a][n]] = (u32x2){cvtpk(s0, s1), cvtpk(s2, s3)};
            }
        }
    }
}

/* ------------------------------------------------------------------ */
__global__ __launch_bounds__(256, 4) void mega_kernel(
    const float* __restrict__ states, const float* __restrict__ latent,
    const float* __restrict__ cnnbf_b,
    const float* __restrict__ rb_conv1_b, const float* __restrict__ rb_conv2_b,
    const float* __restrict__ rb_lfc1_b, const float* __restrict__ rb_lfc2_b,
    const float* __restrict__ mlp1_fc1_b,
    const int* __restrict__ recv_idx, const int* __restrict__ send_idx,
    const float* __restrict__ ws, float* __restrict__ hbar) {

    const int ge0 = blockIdx.x * 2;                /* two edges per block */
    const int tid  = threadIdx.x;
    const int lane = tid & 63;
    const int wv   = tid >> 6;
    const int row0 = lane & 15, g0 = lane >> 4;
    const int mi = wv & 1, ni = wv >> 1;

    __shared__ __align__(16) unsigned short xTb[2*54*64];  /* bf16 trunk, swizzled */
    __shared__ __align__(16) unsigned short hTb[2*54*64];
    __shared__ __align__(16) unsigned short lat_bfb[2*64];
    __shared__ __align__(16) float cond_sb[2*512];

    const unsigned short* bfp = (const unsigned short*)((const char*)ws + 8192);
    const short8* AF = (const short8*)bfp;

    /* per-wave output-tile addresses (invariant across all conv passes) */
    int dixs[2][2];
    const bool skip1 = (ni == 1) && (row0 < 14);
#pragma unroll
    for (int a = 0; a < 2; ++a) {
        const int fo0 = (mi*2 + a)*16 + g0*4;
#pragma unroll
        for (int n = 0; n < 2; ++n) {
            const int t = ((n == 0) ? ni*32 : (ni == 0 ? 16 : 34)) + row0;
            const int rw = t + 2;
            dixs[a][n] = rw*64 + ((((fo0 >> 3) ^ (rw & 7))) << 3) + (fo0 & 7);
        }
    }

    /* ---- stage 0: zero pads, gather both edges ---- */
    for (int z = tid; z < 512; z += 256) {
        const int edz = z >> 8, rr = (z >> 6) & 3, cc = z & 63;
        const int row = (rr < 2) ? rr : 50 + rr;
        xTb[edz*XSTRIDE + row*64 + cc] = 0;
        hTb[edz*XSTRIDE + row*64 + cc] = 0;
    }
    if (tid < 8) {                                   /* x0 pad rows 0,51,52,53 */
        const int edz = tid >> 2, q = tid & 3;
        const int rz = (q == 0) ? 0 : 50 + q;
        short8 zz = {0,0,0,0,0,0,0,0};
        *(short8*)&hTb[edz*XSTRIDE + X0OFF + rz*8] = zz;
    }
    const int b0_ = ge0 / NE_,       e0_ = ge0 % NE_;
    const int b1_ = (ge0+1) / NE_,   e1_ = (ge0+1) % NE_;
    const int rv0 = recv_idx[e0_], sd0 = send_idx[e0_];
    const int rv1 = recv_idx[e1_], sd1 = send_idx[e1_];
    {
        const int ed = tid >> 7, t = tid & 127;      /* one thread per (edge,t) */
        if (t < T_) {
            const int bsel = ed ? b1_ : b0_;
            const int rv = ed ? rv1 : rv0, sd = ed ? sd1 : sd0;
            const f32x4 r4 = *(const f32x4*)&states[((bsel*NO_ + rv)*T_ + t)*SD_];
            const f32x4 s4 = *(const f32x4*)&states[((bsel*NO_ + sd)*T_ + t)*SD_];
            u32x4 q4;
            q4[0] = cvtpk(r4[0], r4[1]); q4[1] = cvtpk(r4[2], r4[3]);
            q4[2] = cvtpk(s4[0], s4[1]); q4[3] = cvtpk(s4[2], s4[3]);
            *(u32x4*)&hTb[ed*XSTRIDE + X0OFF + (t + 1)*8] = q4;
        }
    }
    if (tid < 128) {
        const int edz = tid >> 6, c = tid & 63;
        const int bsel = edz ? b1_ : b0_, esel = edz ? e1_ : e0_;
        lat_bfb[edz*64 + c] = f2bf(latent[(bsel*NE_ + esel)*64 + c]);
    }
    __syncthreads();

    /* ---- stage 1: conv0 via MFMA (A shared) + rb conds (B shared) ---- */
    {
        const int t0a = ni * 32;
        const int sa = t0a + row0 + g0;
        const int sb = (ni == 0) ? (sa + 16) : (sa + 2);
        short8 a0 = AF[FI_C0A + (mi*2 + 0)*64 + lane];
        short8 a1 = AF[FI_C0A + (mi*2 + 1)*64 + lane];
        const f32x4 z4 = {0.f,0.f,0.f,0.f};
#pragma unroll
        for (int ed = 0; ed < 2; ++ed) {
            const unsigned short* xp = hTb + ed*XSTRIDE + X0OFF;
            short8 b0 = *(const short8*)&xp[sa * 8];
            short8 b1 = *(const short8*)&xp[sb * 8];
            f32x4 c00 = MFMA(a0, b0, z4), c01 = MFMA(a0, b1, z4);
            f32x4 c10 = MFMA(a1, b0, z4), c11 = MFMA(a1, b1, z4);
            unsigned short* xw = xTb + ed*XSTRIDE;
#pragma unroll
            for (int a = 0; a < 2; ++a) {
                const int fo0 = (mi*2 + a)*16 + g0*4;
                const f32x4 cb4 = *(const f32x4*)&cnnbf_b[fo0];
#pragma unroll
                for (int n = 0; n < 2; ++n) {
                    if (n == 1 && skip1) continue;
                    const f32x4 A = (a == 0) ? ((n == 0) ? c00 : c01)
                                             : ((n == 0) ? c10 : c11);
                    const float s0 = swish_(A[0] + cb4[0]);
                    const float s1 = swish_(A[1] + cb4[1]);
                    const float s2 = swish_(A[2] + cb4[2]);
                    const float s3 = swish_(A[3] + cb4[3]);
                    *(u32x2*)&xw[dixs[a][n]] = (u32x2){cvtpk(s0, s1), cvtpk(s2, s3)};
                }
            }
        }
        /* rb conds: wave = (rb, which); weight B-frags shared across edges */
        short8 la0_0 = *(const short8*)&lat_bfb[g0 * 8];
        short8 la1_0 = *(const short8*)&lat_bfb[32 + g0 * 8];
        short8 la0_1 = *(const short8*)&lat_bfb[64 + g0 * 8];
        short8 la1_1 = *(const short8*)&lat_bfb[96 + g0 * 8];
        const int rbq = wv >> 1, whq = wv & 1;
        const float* cbias = (whq ? rb_lfc2_b : rb_lfc1_b) + rbq*128;
#pragma unroll
        for (int q8 = 0; q8 < 8; ++q8) {
            short8 w0 = AF[FI_RBL + ((wv*8 + q8)*2 + 0)*64 + lane];
            short8 w1 = AF[FI_RBL + ((wv*8 + q8)*2 + 1)*64 + lane];
            f32x4 d0 = MFMA(la1_0, w1, MFMA(la0_0, w0, z4));
            f32x4 d1 = MFMA(la1_1, w1, MFMA(la0_1, w0, z4));
            if (g0 == 0) {
                const int o = q8*16 + row0;
                cond_sb[rbq*256 + whq*128 + o]       = d0[0] + cbias[o];
                cond_sb[512 + rbq*256 + whq*128 + o] = d1[0] + cbias[o];
            }
        }
    }
    __syncthreads();

    /* ---- stage 2: residual blocks (2 edges interleaved) ---- */
#pragma unroll 1
    for (int rb = 0; rb < 2; ++rb) {
        const float* c0 = cond_sb + rb*256;
        const float* c1 = cond_sb + 512 + rb*256;
        convpass2e<false>(AF, (rb*2 + 0)*2560, xTb, hTb, rb_conv1_b + rb*64,
                          c0, c0 + 64, c1, c1 + 64, dixs, skip1,
                          lane, row0, g0, mi, ni);
        __syncthreads();
        convpass2e<true>(AF, (rb*2 + 1)*2560, hTb, xTb, rb_conv2_b + rb*64,
                         c0 + 128, c0 + 192, c1 + 128, c1 + 192, dixs, skip1,
                         lane, row0, g0, mi, ni);
        __syncthreads();
    }

    /* ---- stage 3: windowed MLP fc1 (A shared) + folded mean ---- */
    {
        const int h = g0, nw = row0;
        f32x4 acc3[2];
        acc3[0] = (f32x4){0.f,0.f,0.f,0.f}; acc3[1] = acc3[0];
        const int nwe = (nw < 15) ? nw : 14;
        const int nwrow = 3*nwe + 2;
#pragma unroll
        for (int kk = 0; kk < 16; ++kk) {
            short8 a = AF[FI_FC1 + (wv*16 + kk)*64 + lane];
            const int row = nwrow + (kk >> 1);
            const int g   = ((kk & 1) << 2) + h;
            const int off = row*64 + ((g ^ (row & 7)) << 3);
#pragma unroll
            for (int ed = 0; ed < 2; ++ed) {
                short8 bfr = *(const short8*)&xTb[ed*XSTRIDE + off];
                acc3[ed] = MFMA(a, bfr, acc3[ed]);
            }
        }
        const f32x4 fb = *(const f32x4*)&mlp1_fc1_b[wv*16 + h*4];
#pragma unroll
        for (int ed = 0; ed < 2; ++ed) {
            float red[4];
#pragma unroll
            for (int r = 0; r < 4; ++r) {
                float v = (nw < 15) ? swish_(acc3[ed][r] + fb[r]) : 0.f;
                v += __shfl_xor(v, 1); v += __shfl_xor(v, 2);
                v += __shfl_xor(v, 4); v += __shfl_xor(v, 8);
                red[r] = v * (1.f / 15.f);
            }
            if (nw == 0) {
                f32x4 o4; o4[0] = red[0]; o4[1] = red[1]; o4[2] = red[2]; o4[3] = red[3];
                *(f32x4*)&hbar[(ge0 + ed)*64 + wv*16 + h*4] = o4;
            }
        }
    }
}

/* ---------------- tail: fc2 + 3 cond-MLP blocks + head, 64 edges/block ---- */
__global__ __launch_bounds__(256) void tail_kernel(
    const float* __restrict__ latent,
    const float* __restrict__ fc2b_g,
    const float* __restrict__ mlf1b, const float* __restrict__ mlf2b,
    const float* __restrict__ mll1b, const float* __restrict__ mll2b,
    const float* __restrict__ em_w, const float* __restrict__ em_b,
    const float* __restrict__ ws, const float* __restrict__ hbar,
    float* __restrict__ out) {

    const int m0 = blockIdx.x * 64;
    const int tid = threadIdx.x, lane = tid & 63, wv = tid >> 6;
    const int row15 = lane & 15, hgp = lane >> 4;
    const int o_l = wv*16 + row15;                 /* this lane's output col */

    __shared__ __align__(16) unsigned short Hb[2][64*64];  /* bf16, swizzled */
    __shared__ float V[64][68];                            /* fp32 running vec */
    __shared__ float em_s[64];

    const unsigned short* bfp = (const unsigned short*)((const char*)ws + 8192);
    const short8* AFp = (const short8*)bfp;

    if (tid < 64) em_s[tid] = em_w[tid];

    /* load hbar -> Hb[0] */
    {
        const int e = tid >> 2, q = tid & 3;
        const f32x4* src = (const f32x4*)&hbar[(m0 + e)*64 + q*16];
#pragma unroll
        for (int v4 = 0; v4 < 4; ++v4) {
            f32x4 x = src[v4];
            const int o0 = q*16 + v4*4;
            const int slot = o0 >> 3, half = (o0 >> 2) & 1;
            u16x4 p; p[0]=f2bf(x[0]); p[1]=f2bf(x[1]); p[2]=f2bf(x[2]); p[3]=f2bf(x[3]);
            *(u16x4*)&Hb[0][e*64 + ((slot ^ (e & 7)) << 3) + half*4] = p;
        }
    }
    __syncthreads();

    /* latent A-frags, cached */
    short8 lf[4][2];
#pragma unroll
    for (int m = 0; m < 4; ++m)
#pragma unroll
        for (int kk = 0; kk < 2; ++kk) {
            const float* lp = &latent[(m0 + m*16 + row15)*64 + kk*32 + hgp*8];
            f32x4 a = *(const f32x4*)lp, c = *(const f32x4*)(lp + 4);
            short8 f;
            f[0]=f2bf(a[0]); f[1]=f2bf(a[1]); f[2]=f2bf(a[2]); f[3]=f2bf(a[3]);
            f[4]=f2bf(c[0]); f[5]=f2bf(c[1]); f[6]=f2bf(c[2]); f[7]=f2bf(c[3]);
            lf[m][kk] = f;
        }

#define RD_A(buf, m, kk) \
    (*(const short8*)&Hb[buf][(m*16 + row15)*64 + ((((kk)*4 + hgp) ^ ((m*16 + row15) & 7)) << 3)])
#define RD_FCP(g, kk)  AFp[FI_FCP + (((g)*4 + wv)*2 + (kk))*64 + lane]
#define RD_CND(mb, nt, kk) AFp[FI_CONDP + (((mb)*16 + (nt))*2 + (kk))*64 + lane]

    /* GEMM0: stage3 fc2 */
    f32x4 D[4];
#pragma unroll
    for (int m = 0; m < 4; ++m) D[m] = (f32x4){0.f,0.f,0.f,0.f};
#pragma unroll
    for (int kk = 0; kk < 2; ++kk) {
        short8 bfr = RD_FCP(0, kk);
#pragma unroll
        for (int m = 0; m < 4; ++m) D[m] = MFMA(RD_A(0, m, kk), bfr, D[m]);
    }
    {
        const float bias = fc2b_g[o_l];
#pragma unroll
        for (int m = 0; m < 4; ++m)
#pragma unroll
            for (int r = 0; r < 4; ++r) {
                const int ee = m*16 + hgp*4 + r;
                const float v = D[m][r] + bias;
                V[ee][o_l] = v;
                Hb[1][ee*64 + ((((o_l >> 3) ^ (ee & 7))) << 3) + (o_l & 7)] = f2bf(v);
            }
    }
    __syncthreads();

    /* 3 cond-MLP blocks */
#pragma unroll 1
    for (int mb = 0; mb < 3; ++mb) {
        f32x4 G1[4], B1[4];
#pragma unroll
        for (int m = 0; m < 4; ++m) { G1[m] = (f32x4){0.f,0.f,0.f,0.f}; B1[m] = G1[m]; }
#pragma unroll
        for (int kk = 0; kk < 2; ++kk) {
            short8 bg = RD_CND(mb, wv,     kk);
            short8 bb = RD_CND(mb, wv + 4, kk);
#pragma unroll
            for (int m = 0; m < 4; ++m) {
                G1[m] = MFMA(lf[m][kk], bg, G1[m]);
                B1[m] = MFMA(lf[m][kk], bb, B1[m]);
            }
        }
        f32x4 D1[4];
#pragma unroll
        for (int m = 0; m < 4; ++m) D1[m] = (f32x4){0.f,0.f,0.f,0.f};
#pragma unroll
        for (int kk = 0; kk < 2; ++kk) {
            short8 bfr = RD_FCP(1 + mb*2, kk);
#pragma unroll
            for (int m = 0; m < 4; ++m) D1[m] = MFMA(RD_A(1, m, kk), bfr, D1[m]);
        }
        {
            const float bfc  = mlf1b[mb*64 + o_l];
            const float bg1  = mll1b[mb*128 + o_l];
            const float bb1  = mll1b[mb*128 + 64 + o_l];
#pragma unroll
            for (int m = 0; m < 4; ++m)
#pragma unroll
                for (int r = 0; r < 4; ++r) {
                    const int ee = m*16 + hgp*4 + r;
                    const float h1 = swish_((G1[m][r] + bg1) * (D1[m][r] + bfc)
                                            + (B1[m][r] + bb1));
                    Hb[0][ee*64 + ((((o_l >> 3) ^ (ee & 7))) << 3) + (o_l & 7)] = f2bf(h1);
                }
        }
        __syncthreads();

        f32x4 G2[4], B2[4];
#pragma unroll
        for (int m = 0; m < 4; ++m) { G2[m] = (f32x4){0.f,0.f,0.f,0.f}; B2[m] = G2[m]; }
#pragma unroll
        for (int kk = 0; kk < 2; ++kk) {
            short8 bg = RD_CND(mb, wv + 8,  kk);
            short8 bb = RD_CND(mb, wv + 12, kk);
#pragma unroll
            for (int m = 0; m < 4; ++m) {
                G2[m] = MFMA(lf[m][kk], bg, G2[m]);
                B2[m] = MFMA(lf[m][kk], bb, B2[m]);
            }
        }
        f32x4 D2[4];
#pragma unroll
        for (int m = 0; m < 4; ++m) D2[m] = (f32x4){0.f,0.f,0.f,0.f};
#pragma unroll
        for (int kk = 0; kk < 2; ++kk) {
            short8 bfr = RD_FCP(2 + mb*2, kk);
#pragma unroll
            for (int m = 0; m < 4; ++m) D2[m] = MFMA(RD_A(0, m, kk), bfr, D2[m]);
        }
        {
            const float bfc  = mlf2b[mb*64 + o_l];
            const float bg2  = mll2b[mb*128 + o_l];
            const float bb2  = mll2b[mb*128 + 64 + o_l];
#pragma unroll
            for (int m = 0; m < 4; ++m)
#pragma unroll
                for (int r = 0; r < 4; ++r) {
                    const int ee = m*16 + hgp*4 + r;
                    const float add = swish_((G2[m][r] + bg2) * (D2[m][r] + bfc)
                                             + (B2[m][r] + bb2));
                    const float vn = V[ee][o_l] + add;
                    V[ee][o_l] = vn;
                    Hb[1][ee*64 + ((((o_l >> 3) ^ (ee & 7))) << 3) + (o_l & 7)] = f2bf(vn);
                }
        }
        __syncthreads();
    }

    /* head */
    if (tid < 64) {
        const int ee = tid;
        float acc = em_b[0];
#pragma unroll 16
        for (int j = 0; j < 64; ++j) {
            const int o = (j + ee) & 63;
            acc += V[ee][o] * em_s[o];
        }
        out[m0 + ee] = acc;
    }
}

extern "C" void kernel_launch(void* const* d_in, const int* in_sizes, int n_in,
                              void* d_out, int out_size, void* d_ws, size_t ws_size,
                              hipStream_t stream) {
    const float* states   = (const float*)d_in[0];
    const float* latent   = (const float*)d_in[1];
    const float* cnnbf_w  = (const float*)d_in[2];
    const float* cnnbf_b  = (const float*)d_in[3];
    const float* rb1w     = (const float*)d_in[4];
    const float* rb1b     = (const float*)d_in[5];
    const float* rb2w     = (const float*)d_in[6];
    const float* rb2b     = (const float*)d_in[7];
    const float* rbl1w    = (const float*)d_in[8];
    const float* rbl1b    = (const float*)d_in[9];
    const float* rbl2w    = (const float*)d_in[10];
    const float* rbl2b    = (const float*)d_in[11];
    const float* fc1w     = (const float*)d_in[12];
    const float* fc1b     = (const float*)d_in[13];
    const float* fc2w     = (const float*)d_in[14];
    const float* fc2b     = (const float*)d_in[15];
    const float* mlf1w    = (const float*)d_in[16];
    const float* mlf1b    = (const float*)d_in[17];
    const float* mlf2w    = (const float*)d_in[18];
    const float* mlf2b    = (const float*)d_in[19];
    const float* mll1w    = (const float*)d_in[20];
    const float* mll1b    = (const float*)d_in[21];
    const float* mll2w    = (const float*)d_in[22];
    const float* mll2b    = (const float*)d_in[23];
    const float* em_w     = (const float*)d_in[24];
    const float* em_b     = (const float*)d_in[25];
    const int*   recv_idx = (const int*)d_in[26];
    const int*   send_idx = (const int*)d_in[27];
    float* ws  = (float*)d_ws;
    float* out = (float*)d_out;
    float* hbar = ws + HBAR_F32;

    prep_kernel<<<(N_BF16 + 255) / 256, 256, 0, stream>>>(
        cnnbf_w, rb1w, rb2w, fc1w, fc2w, rbl1w, rbl2w, mll1w, mll2w, mlf1w, mlf2w, ws);

    mega_kernel<<<B_ * NE_ / 2, 256, 0, stream>>>(
        states, latent, cnnbf_b, rb1b, rb2b, rbl1b, rbl2b, fc1b,
        recv_idx, send_idx, ws, hbar);

    tail_kernel<<<(B_ * NE_) / 64, 256, 0, stream>>>(
        latent, fc2b, mlf1b, mlf2b, mll1b, mll2b, em_w, em_b, ws, hbar, out);
}